// Round 1
// baseline (253.426 us; speedup 1.0000x reference)
//
#include <hip/hip_runtime.h>

#define N_NODES 100000
#define N_EDGES 640000
#define F 128

// ---------------------------------------------------------------------------
// Kernel 1: node projections.
//   A[n,j] = sum_k h[n,k] * W1[k,j]      + b1[j]   (b1 folded here)
//   B[n,j] = sum_k h[n,k] * W1[128+k,j]
// 32 nodes per block (256 threads = 4 waves, 8 nodes per wave).
// Lane jl = tid&63 owns output columns j = jl*4..jl*4+3 (jl<32 -> A, else B).
// W1 staged in LDS in 16-row k-tiles; h read via wave-uniform scalar loads.
// ---------------------------------------------------------------------------
__global__ __launch_bounds__(256) void node_proj(
    const float* __restrict__ h, const float* __restrict__ W1,
    const float* __restrict__ b1, float* __restrict__ A, float* __restrict__ B)
{
    __shared__ float wt[16 * 256];   // 16 KB k-tile of W1 (cols 0..255 = A-half|B-half)

    const int tid  = threadIdx.x;
    const int jl   = tid & 63;
    const int wave = __builtin_amdgcn_readfirstlane(tid >> 6);  // force SGPR
    const int n0   = blockIdx.x * 32 + wave * 8;
    const float* hp = h + (size_t)n0 * F;   // wave-uniform base -> s_load path

    float4 acc[8];
#pragma unroll
    for (int i = 0; i < 8; ++i) acc[i] = make_float4(0.f, 0.f, 0.f, 0.f);

    const float4* W1v = (const float4*)W1;   // W1 is [256][128] f32, row = 32 float4

    for (int kt = 0; kt < 8; ++kt) {
        __syncthreads();
        // stage rows k = kt*16 .. kt*16+15 for all 256 logical cols
#pragma unroll
        for (int i = 0; i < 4; ++i) {
            int f  = tid + i * 256;          // float4 index in [0,1024)
            int kk = f >> 6;
            int jq = f & 63;                 // float4 col in [0,64): <32 A-half, >=32 B-half
            int k  = kt * 16 + kk;
            int gsrc = (jq < 32) ? (k * 32 + jq) : ((128 + k) * 32 + (jq - 32));
            ((float4*)wt)[f] = W1v[gsrc];
        }
        __syncthreads();

        const float4* wt4 = (const float4*)wt;
#pragma unroll
        for (int kk = 0; kk < 16; ++kk) {
            float4 w = wt4[kk * 64 + jl];    // stride-1 across wave: conflict-free b128
            int k = kt * 16 + kk;
#pragma unroll
            for (int i = 0; i < 8; ++i) {
                float hv = hp[i * F + k];    // wave-uniform -> scalar load + broadcast
                acc[i].x = fmaf(hv, w.x, acc[i].x);
                acc[i].y = fmaf(hv, w.y, acc[i].y);
                acc[i].z = fmaf(hv, w.z, acc[i].z);
                acc[i].w = fmaf(hv, w.w, acc[i].w);
            }
        }
    }

    // epilogue: lanes 0..31 -> A (add b1), lanes 32..63 -> B
    const bool isA = (jl < 32);
    const int  jj  = (jl & 31) * 4;
    float4 bias = make_float4(0.f, 0.f, 0.f, 0.f);
    if (isA) bias = ((const float4*)b1)[jl];
    float* outp = (isA ? A : B) + (size_t)n0 * F + jj;
#pragma unroll
    for (int i = 0; i < 8; ++i) {
        float4 v = acc[i];
        v.x += bias.x; v.y += bias.y; v.z += bias.z; v.w += bias.w;
        *(float4*)(outp + (size_t)i * F) = v;
    }
}

// ---------------------------------------------------------------------------
// Kernel 2: per-edge score.
//   score[e] = b2 + sum_j relu(A[src[e],j] + B[dst[e],j]) * W2[j]
// 16 lanes per edge, 8 channels per lane (2x float4), shfl_xor reduction.
// ---------------------------------------------------------------------------
__global__ __launch_bounds__(256) void edge_score(
    const float* __restrict__ A, const float* __restrict__ B,
    const int* __restrict__ src, const int* __restrict__ dst,
    const float* __restrict__ W2, const float* __restrict__ b2,
    float* __restrict__ out)
{
    const int tid = threadIdx.x;
    const int sub = tid & 15;                    // lane within edge-group
    const int e   = blockIdx.x * 16 + (tid >> 4);
    const int j0  = sub * 8;

    const float4 w2a = ((const float4*)W2)[sub * 2];
    const float4 w2b = ((const float4*)W2)[sub * 2 + 1];

    const int s = src[e];
    const int d = dst[e];
    const float4* Ap = (const float4*)(A + (size_t)s * F + j0);
    const float4* Bp = (const float4*)(B + (size_t)d * F + j0);
    float4 a0 = Ap[0], a1 = Ap[1];
    float4 b0 = Bp[0], b1v = Bp[1];

    float sacc = 0.f;
    sacc = fmaf(fmaxf(a0.x + b0.x, 0.f), w2a.x, sacc);
    sacc = fmaf(fmaxf(a0.y + b0.y, 0.f), w2a.y, sacc);
    sacc = fmaf(fmaxf(a0.z + b0.z, 0.f), w2a.z, sacc);
    sacc = fmaf(fmaxf(a0.w + b0.w, 0.f), w2a.w, sacc);
    sacc = fmaf(fmaxf(a1.x + b1v.x, 0.f), w2b.x, sacc);
    sacc = fmaf(fmaxf(a1.y + b1v.y, 0.f), w2b.y, sacc);
    sacc = fmaf(fmaxf(a1.z + b1v.z, 0.f), w2b.z, sacc);
    sacc = fmaf(fmaxf(a1.w + b1v.w, 0.f), w2b.w, sacc);

    // reduce across the 16 lanes of this edge (xor masks stay inside group)
    sacc += __shfl_xor(sacc, 1);
    sacc += __shfl_xor(sacc, 2);
    sacc += __shfl_xor(sacc, 4);
    sacc += __shfl_xor(sacc, 8);

    if (sub == 0) out[e] = sacc + b2[0];
}

extern "C" void kernel_launch(void* const* d_in, const int* in_sizes, int n_in,
                              void* d_out, int out_size, void* d_ws, size_t ws_size,
                              hipStream_t stream) {
    const float* h   = (const float*)d_in[0];
    const int*   src = (const int*)d_in[1];
    const int*   dst = (const int*)d_in[2];
    const float* W1  = (const float*)d_in[3];
    const float* b1  = (const float*)d_in[4];
    const float* W2  = (const float*)d_in[5];
    const float* b2  = (const float*)d_in[6];
    float* out = (float*)d_out;

    float* A = (float*)d_ws;                       // [N_NODES][128]
    float* B = A + (size_t)N_NODES * F;            // [N_NODES][128]

    node_proj<<<N_NODES / 32, 256, 0, stream>>>(h, W1, b1, A, B);
    edge_score<<<N_EDGES / 16, 256, 0, stream>>>(A, B, src, dst, W2, b2, out);
}

// Round 2
// 171.374 us; speedup vs baseline: 1.4788x; 1.4788x over previous
//
#include <hip/hip_runtime.h>

#define N_NODES 100000
#define N_EDGES 640000
#define F 128

typedef __attribute__((ext_vector_type(8))) short short8;
typedef __attribute__((ext_vector_type(4))) float float4v;

// RNE float -> bf16 bits
static __device__ __forceinline__ unsigned short f2bf(float f) {
    unsigned int u = __float_as_uint(f);
    u += 0x7fffu + ((u >> 16) & 1u);
    return (unsigned short)(u >> 16);
}

// ---------------------------------------------------------------------------
// Kernel 0: transpose+convert W1 (fp32 [256][128]) into Wt bf16 [256][128]:
//   Wt[n][k] = W1[(n&128)+k][n&127]
// so n<128 rows give the A-half (W1[k][n]) and n>=128 the B-half.
// ---------------------------------------------------------------------------
__global__ __launch_bounds__(256) void prep_wt(
    const float* __restrict__ W1, unsigned short* __restrict__ Wt)
{
    int id = blockIdx.x * 256 + threadIdx.x;       // 0 .. 32767
    int n = id >> 7, k = id & 127;
    float v = W1[((n & 128) + k) * 128 + (n & 127)];
    Wt[id] = f2bf(v);
}

// ---------------------------------------------------------------------------
// Kernel 1: node projections via bf16 MFMA.
//   y=0: A[m][n] = sum_k h[m][k]*W1[k][n] + b1[n]   (bf16 out)
//   y=1: B[m][n] = sum_k h[m][k]*W1[128+k][n]       (bf16 out)
// Block: 256 threads (4 waves), M-tile=64 nodes, N=128, K=128 in one pass.
// Wave w owns cols [w*32, w*32+32). mfma_f32_16x16x32_bf16:
//   A-frag: A[m=l16][k=quad*8+j]; B-frag: B[k=quad*8+j][n=l16];
//   C/D:    row=quad*4+reg, col=l16.
// LDS rows padded to 136 shorts (272 B): 16B-aligned, 2-way bank alias (free).
// ---------------------------------------------------------------------------
__global__ __launch_bounds__(256) void node_proj(
    const float* __restrict__ h, const unsigned short* __restrict__ Wt,
    const float* __restrict__ b1,
    unsigned short* __restrict__ A, unsigned short* __restrict__ B)
{
    __shared__ unsigned short h_lds[64 * 136];    // 17.4 KB
    __shared__ unsigned short w_lds[128 * 136];   // 34.8 KB

    const int tid  = threadIdx.x;
    const int y    = blockIdx.y;
    const int node0 = blockIdx.x * 64;

    // ---- stage h tile: 64 rows x 128 fp32 -> bf16 ----
#pragma unroll
    for (int i = 0; i < 8; ++i) {
        int idx = i * 256 + tid;                  // float4 index, 0..2047
        int m = idx >> 5, c4 = idx & 31;
        int row_g = node0 + m; if (row_g >= N_NODES) row_g = N_NODES - 1;
        float4 v = *(const float4*)(h + (size_t)row_g * F + c4 * 4);
        uint2 p;
        p.x = (unsigned)f2bf(v.x) | ((unsigned)f2bf(v.y) << 16);
        p.y = (unsigned)f2bf(v.z) | ((unsigned)f2bf(v.w) << 16);
        *(uint2*)&h_lds[m * 136 + c4 * 4] = p;
    }
    // ---- stage Wt half: 128 rows x 128 bf16 (already converted) ----
#pragma unroll
    for (int i = 0; i < 8; ++i) {
        int idx = i * 256 + tid;                  // 16B-chunk index, 0..2047
        int n = idx >> 4, c = idx & 15;
        uint4 v = *(const uint4*)(Wt + (size_t)(y * 128 + n) * F + c * 8);
        *(uint4*)&w_lds[n * 136 + c * 8] = v;
    }
    __syncthreads();

    const int lane = tid & 63;
    const int l16  = lane & 15;
    const int quad = lane >> 4;
    const int w    = tid >> 6;          // wave id 0..3
    const int n0w  = w * 32;
    const int kq   = quad * 8;

    float4v acc[4][2];
#pragma unroll
    for (int i = 0; i < 4; ++i)
#pragma unroll
        for (int j = 0; j < 2; ++j) acc[i][j] = (float4v){0.f, 0.f, 0.f, 0.f};

#pragma unroll
    for (int k0 = 0; k0 < 128; k0 += 32) {
        short8 af[4], bf[2];
#pragma unroll
        for (int i = 0; i < 4; ++i)
            af[i] = *(const short8*)&h_lds[(i * 16 + l16) * 136 + k0 + kq];
#pragma unroll
        for (int j = 0; j < 2; ++j)
            bf[j] = *(const short8*)&w_lds[(n0w + j * 16 + l16) * 136 + k0 + kq];
#pragma unroll
        for (int i = 0; i < 4; ++i)
#pragma unroll
            for (int j = 0; j < 2; ++j)
                acc[i][j] = __builtin_amdgcn_mfma_f32_16x16x32_bf16(
                    af[i], bf[j], acc[i][j], 0, 0, 0);
    }

    unsigned short* outp = (y == 0) ? A : B;
#pragma unroll
    for (int j = 0; j < 2; ++j) {
        int col = n0w + j * 16 + l16;
        float bias = (y == 0) ? b1[col] : 0.f;
#pragma unroll
        for (int i = 0; i < 4; ++i) {
#pragma unroll
            for (int r = 0; r < 4; ++r) {
                int row_g = node0 + i * 16 + quad * 4 + r;
                if (row_g < N_NODES)
                    outp[(size_t)row_g * F + col] = f2bf(acc[i][j][r] + bias);
            }
        }
    }
}

// ---------------------------------------------------------------------------
// Kernel 2: per-edge score from bf16 A,B.
//   score[e] = b2 + sum_j relu(A[src,j]+B[dst,j]) * W2[j]
// 8 lanes/edge, 16 channels/lane (2x 16B loads per side), fp32 math.
// ---------------------------------------------------------------------------
__global__ __launch_bounds__(256) void edge_score(
    const unsigned short* __restrict__ A, const unsigned short* __restrict__ B,
    const int* __restrict__ src, const int* __restrict__ dst,
    const float* __restrict__ W2, const float* __restrict__ b2,
    float* __restrict__ out)
{
    const int tid = threadIdx.x;
    const int sub = tid & 7;
    const int e   = blockIdx.x * 32 + (tid >> 3);
    const int j0  = sub * 16;

    const int s = src[e];
    const int d = dst[e];
    const uint4* Ap = (const uint4*)(A + (size_t)s * F + j0);
    const uint4* Bp = (const uint4*)(B + (size_t)d * F + j0);
    uint4 a0 = Ap[0], a1 = Ap[1];
    uint4 b0 = Bp[0], b1v = Bp[1];
    const float4* Wp = (const float4*)(W2 + j0);
    float4 w0 = Wp[0], w1 = Wp[1], w2 = Wp[2], w3 = Wp[3];

    float sacc = 0.f;
#define TERM(UA, UB, WL, WH)                                                   \
    {                                                                          \
        float fa0 = __uint_as_float((UA) << 16);                               \
        float fa1 = __uint_as_float((UA) & 0xFFFF0000u);                       \
        float fb0 = __uint_as_float((UB) << 16);                               \
        float fb1 = __uint_as_float((UB) & 0xFFFF0000u);                       \
        sacc = fmaf(fmaxf(fa0 + fb0, 0.f), (WL), sacc);                        \
        sacc = fmaf(fmaxf(fa1 + fb1, 0.f), (WH), sacc);                        \
    }
    TERM(a0.x, b0.x, w0.x, w0.y) TERM(a0.y, b0.y, w0.z, w0.w)
    TERM(a0.z, b0.z, w1.x, w1.y) TERM(a0.w, b0.w, w1.z, w1.w)
    TERM(a1.x, b1v.x, w2.x, w2.y) TERM(a1.y, b1v.y, w2.z, w2.w)
    TERM(a1.z, b1v.z, w3.x, w3.y) TERM(a1.w, b1v.w, w3.z, w3.w)
#undef TERM

    sacc += __shfl_xor(sacc, 1);
    sacc += __shfl_xor(sacc, 2);
    sacc += __shfl_xor(sacc, 4);

    if (sub == 0) out[e] = sacc + b2[0];
}

extern "C" void kernel_launch(void* const* d_in, const int* in_sizes, int n_in,
                              void* d_out, int out_size, void* d_ws, size_t ws_size,
                              hipStream_t stream) {
    const float* h   = (const float*)d_in[0];
    const int*   src = (const int*)d_in[1];
    const int*   dst = (const int*)d_in[2];
    const float* W1  = (const float*)d_in[3];
    const float* b1  = (const float*)d_in[4];
    const float* W2  = (const float*)d_in[5];
    const float* b2  = (const float*)d_in[6];
    float* out = (float*)d_out;

    // workspace layout (bf16): Wt[256][128] | A[100000][128] | B[100000][128]
    unsigned short* Wt = (unsigned short*)d_ws;
    unsigned short* A  = Wt + 256 * 128;
    unsigned short* B  = A + (size_t)N_NODES * F;

    prep_wt<<<128, 256, 0, stream>>>(W1, Wt);
    node_proj<<<dim3((N_NODES + 63) / 64, 2), 256, 0, stream>>>(h, Wt, b1, A, B);
    edge_score<<<N_EDGES / 32, 256, 0, stream>>>(A, B, src, dst, W2, b2, out);
}